// Round 10
// baseline (531.881 us; speedup 1.0000x reference)
//
#include <hip/hip_runtime.h>
#include <stdint.h>

// Problem constants
#define BATCH 4096
#define DIMD  256
#define DIMH  1024
#define EPAD  264       // E tile row stride in bf16 elems (256 + 8 pad)
#define NEPW  163840    // packed words per stage: 10*4096*256/64

typedef __attribute__((ext_vector_type(8))) short short8;
typedef __attribute__((ext_vector_type(4))) float float4v;

struct Keys4 { uint32_t a[4]; uint32_t b[4]; };

// ---------------- threefry2x32 (JAX-compatible, 20 rounds) ----------------
__host__ __device__ static inline uint32_t rotl32(uint32_t v, int r) {
#ifdef __HIP_DEVICE_COMPILE__
    return __builtin_amdgcn_alignbit(v, v, 32 - r);   // 1-inst funnel rotate
#else
    return (v << r) | (v >> (32 - r));
#endif
}

__host__ __device__ static inline void tf2x32(uint32_t k0, uint32_t k1,
                                              uint32_t c0, uint32_t c1,
                                              uint32_t& o0, uint32_t& o1) {
    uint32_t ks0 = k0, ks1 = k1, ks2 = k0 ^ k1 ^ 0x1BD11BDAu;
    uint32_t x0 = c0 + ks0, x1 = c1 + ks1;
#define TF_R4(a, b, c, d)                                   \
    x0 += x1; x1 = rotl32(x1, a); x1 ^= x0;                 \
    x0 += x1; x1 = rotl32(x1, b); x1 ^= x0;                 \
    x0 += x1; x1 = rotl32(x1, c); x1 ^= x0;                 \
    x0 += x1; x1 = rotl32(x1, d); x1 ^= x0;
    TF_R4(13, 15, 26, 6)  x0 += ks1; x1 += ks2 + 1u;
    TF_R4(17, 29, 16, 24) x0 += ks2; x1 += ks0 + 2u;
    TF_R4(13, 15, 26, 6)  x0 += ks0; x1 += ks1 + 3u;
    TF_R4(17, 29, 16, 24) x0 += ks1; x1 += ks2 + 4u;
    TF_R4(13, 15, 26, 6)  x0 += ks2; x1 += ks0 + 5u;
#undef TF_R4
    o0 = x0; o1 = x1;
}

// float -> bf16 (round-to-nearest-even), bit pattern in a short
__device__ static inline short f2bf(float f) {
    uint32_t u = __float_as_uint(f);
    uint32_t r = (u + 0x7FFFu + ((u >> 16) & 1u)) >> 16;
    return (short)r;
}

// ---------------- Prep (fused): W1T, W2B, W2T, Zb0, dv=0, egen stage 0 ----
// Flat index ranges (all boundaries are multiples of 64 so waves never
// straddle — required for the __ballot in the egen range).
__global__ __launch_bounds__(256) void k_prep(
    const float* __restrict__ x,  const float* __restrict__ W1,
    const float* __restrict__ W2, short* __restrict__ W1T,
    short* __restrict__ W2B, short* __restrict__ W2T,
    short* __restrict__ zb, float* __restrict__ dv,
    uint64_t* __restrict__ Ep0, uint32_t ek0, uint32_t ek1)
{
    const int idx = blockIdx.x * 256 + threadIdx.x;
    if (idx < 262144) {                       // W1T[n][d] = bf16(W1[d][n])
        const int n = idx >> 8, d = idx & 255;
        W1T[idx] = f2bf(W1[d * DIMH + n]);
    } else if (idx < 524288) {                // W2B = bf16(W2) row-major
        const int i = idx - 262144;
        W2B[i] = f2bf(W2[i]);
    } else if (idx < 786432) {                // W2T[d][k] = bf16(W2[k][d])
        const int i = idx - 524288;
        const int d = i >> 10, k = i & 1023;
        W2T[i] = f2bf(W2[k * DIMD + d]);
    } else if (idx < 1835008) {               // zb0 = bf16(x)
        const int i = idx - 786432;
        zb[i] = f2bf(x[i]);
    } else if (idx < 1851392) {               // dv = 0 (4*4096 floats)
        dv[idx - 1835008] = 0.0f;
    } else {                                  // egen stage 0: 10.49M bits
        const uint32_t j = (uint32_t)(idx - 1851392);
        uint32_t y0, y1;
        tf2x32(ek0, ek1, 0u, j, y0, y1);
        uint64_t mask = __ballot(((y0 ^ y1) & 1u) != 0u);
        if ((threadIdx.x & 63) == 0)
            Ep0[j >> 6] = mask;
    }
}

// ---------------- Fused K1+K3: h-tile + Hutchinson probes + next egen -----
// Grid (16 n-tiles, 64 batch-tiles) = 1024 blocks. 256 thr = 4 waves; wave
// owns one 16-wide n-subtile: n = nt*64 + wave*16 + col.
// Phase 1 (h): C = Zb(rows b0..63) @ W1T(cols n)^T; tanh epilogue; writes
//   hb (for k_fz2) and keeps s = 1-h^2 in registers (MFMA C-layout of h is
//   identical to the sreg layout the probe loop needs).
// Phase 1.5 (egen-next): this block ballots its 160-word share of the NEXT
//   stage's packed Rademacher bits (~40 ciphers/thread). Pure VALU — hides
//   under other blocks' MFMA/LDS phases (m114 co-issue), removing the
//   90 µs serial k_egen4 from the critical path.
// Phase 2 (probes): per probe expand 2 KB packed bits -> LDS E tile, then
//   u = E@W1T^T, v = E@W2B^T via MFMA; rowacc += u*s*v.
__global__ __launch_bounds__(256) void k_pre_div(
    const short* __restrict__ Zb, const short* __restrict__ W1T,
    const short* __restrict__ W2B, const float* __restrict__ W1,
    const float* __restrict__ b1, float tval,
    const uint64_t* __restrict__ Ep, short* __restrict__ h_bf,
    float* __restrict__ divacc,
    uint64_t* __restrict__ EpNext, uint32_t nk0, uint32_t nk1, int do_egen)
{
    __shared__ short E[64 * EPAD];
    const int t = threadIdx.x;
    const int nt = blockIdx.x;         // fastest-varying: blocks share Zb/Ep rows
    const int b0 = blockIdx.y * 64;
    const int wave = t >> 6, lane = t & 63;
    const int col = lane & 15, kq = lane >> 4;
    const int n = nt * 64 + wave * 16 + col;

    // W1T B-fragments (used by h-phase AND u-MFMA)
    short8 bufr[8];
#pragma unroll
    for (int ks = 0; ks < 8; ++ks)
        bufr[ks] = *(const short8*)&W1T[n * DIMD + ks * 32 + kq * 8];

    // ---- Phase 1: h = tanh(Zb @ W1T^T + t*W1[256] + b1) ----
    float sreg[4][4];
    const float add = tval * W1[DIMD * DIMH + n] + b1[n];
#pragma unroll
    for (int ms = 0; ms < 4; ++ms) {
        float4v acc = {0.f, 0.f, 0.f, 0.f};
#pragma unroll
        for (int ks = 0; ks < 8; ++ks) {
            short8 af = *(const short8*)&Zb[(b0 + ms * 16 + col) * DIMD + ks * 32 + kq * 8];
            acc = __builtin_amdgcn_mfma_f32_16x16x32_bf16(af, bufr[ks], acc, 0, 0, 0);
        }
        // C layout: col = lane&15, row = kq*4 + r (verified m89/m91)
#pragma unroll
        for (int r = 0; r < 4; ++r) {
            float hv = tanhf(acc[r] + add);
            h_bf[(b0 + ms * 16 + kq * 4 + r) * DIMH + n] = f2bf(hv);
            sreg[ms][r] = 1.0f - hv * hv;
        }
    }

    // ---- Phase 1.5: generate next stage's packed bits (block's share) ----
    if (do_egen) {
        const uint32_t bflat = (uint32_t)(blockIdx.y * 16 + blockIdx.x);  // 0..1023
        const uint32_t jbase = bflat * 10240u + (uint32_t)t;
#pragma unroll 2
        for (int w = 0; w < 40; ++w) {
            uint32_t j = jbase + (uint32_t)w * 256u;
            uint32_t y0, y1;
            tf2x32(nk0, nk1, 0u, j, y0, y1);
            uint64_t mask = __ballot(((y0 ^ y1) & 1u) != 0u);
            if (lane == 0)
                EpNext[j >> 6] = mask;
        }
    }

    // W2B B-fragments (v-MFMA), loaded after phase 1 to cap VGPR peak
    short8 bvfr[8];
#pragma unroll
    for (int ks = 0; ks < 8; ++ks)
        bvfr[ks] = *(const short8*)&W2B[n * DIMD + ks * 32 + kq * 8];

    float rowacc[4][4];
#pragma unroll
    for (int a = 0; a < 4; ++a)
#pragma unroll
        for (int r = 0; r < 4; ++r) rowacc[a][r] = 0.0f;

    // ---- Phase 2: 10 probes ----
    // thread t expands word (row = t&63, colgroup = t>>6)
    const int erow = t & 63, ecg = t >> 6;
    short* const edst = &E[erow * EPAD + ecg * 64];
    const uint64_t* const esrc = Ep + (size_t)b0 * 4 + erow * 4 + ecg;

#pragma unroll 1
    for (int probe = 0; probe < 10; ++probe) {
        __syncthreads();   // previous probe's readers done before overwrite
        uint64_t w = esrc[(size_t)probe * BATCH * 4];
#pragma unroll
        for (int i = 0; i < 8; ++i) {
            short8 val;
#pragma unroll
            for (int k = 0; k < 8; ++k)
                val[k] = ((w >> (i * 8 + k)) & 1ull) ? (short)0x3F80 : (short)0xBF80u;
            *(short8*)&edst[i * 8] = val;
        }
        __syncthreads();

#pragma unroll
        for (int ms = 0; ms < 4; ++ms) {
            const short* arow = &E[(ms * 16 + col) * EPAD + kq * 8];
            float4v u = {0.f, 0.f, 0.f, 0.f}, v = {0.f, 0.f, 0.f, 0.f};
#pragma unroll
            for (int ks = 0; ks < 8; ++ks) {
                short8 af = *(const short8*)&arow[ks * 32];
                u = __builtin_amdgcn_mfma_f32_16x16x32_bf16(af, bufr[ks], u, 0, 0, 0);
                v = __builtin_amdgcn_mfma_f32_16x16x32_bf16(af, bvfr[ks], v, 0, 0, 0);
            }
#pragma unroll
            for (int r = 0; r < 4; ++r)
                rowacc[ms][r] += u[r] * sreg[ms][r] * v[r];
        }
    }

#pragma unroll
    for (int ms = 0; ms < 4; ++ms) {
#pragma unroll
        for (int r = 0; r < 4; ++r) {
            float p = rowacc[ms][r];
            p += __shfl_xor(p, 1, 64);
            p += __shfl_xor(p, 2, 64);
            p += __shfl_xor(p, 4, 64);
            p += __shfl_xor(p, 8, 64);
            rowacc[ms][r] = p;
        }
    }
    if (col == 0) {
#pragma unroll
        for (int ms = 0; ms < 4; ++ms)
#pragma unroll
            for (int r = 0; r < 4; ++r)
                atomicAdd(&divacc[b0 + ms * 16 + kq * 4 + r], rowacc[ms][r] * 0.1f);
    }
}

// ---------------- K2: fz = Hb @ W2 + b2 (fp32 out); fuse Zb_next ----------
// MFMA 16x16x32, K=1024 pipelined. Block 256 thr = 4 waves; wave = 16 rows
// x 64 cols (waves tile N=256). Grid = 4096/16 = 256.
__global__ __launch_bounds__(256) void k_fz2(
    const short* __restrict__ Hb, const short* __restrict__ W2T,
    const float* __restrict__ b2, const float* __restrict__ x,
    float* __restrict__ fz, float cnext, int write_zb, short* __restrict__ zb)
{
    const int t = threadIdx.x;
    const int wave = t >> 6, lane = t & 63;
    const int col = lane & 15, kq = lane >> 4;
    const int m0 = blockIdx.x * 16;
    const int n0 = wave * 64;

    float4v acc[4];
#pragma unroll
    for (int ns = 0; ns < 4; ++ns) acc[ns] = (float4v){0.f, 0.f, 0.f, 0.f};

    const short* ap = &Hb[(m0 + col) * DIMH + kq * 8];
    short8 a_cur = *(const short8*)ap;
    short8 b_cur[4];
#pragma unroll
    for (int ns = 0; ns < 4; ++ns)
        b_cur[ns] = *(const short8*)&W2T[(n0 + ns * 16 + col) * DIMH + kq * 8];

    for (int ks = 0; ks < 31; ++ks) {
        short8 a_nxt = *(const short8*)&ap[(ks + 1) * 32];
        short8 b_nxt[4];
#pragma unroll
        for (int ns = 0; ns < 4; ++ns)
            b_nxt[ns] = *(const short8*)&W2T[(n0 + ns * 16 + col) * DIMH + (ks + 1) * 32 + kq * 8];
#pragma unroll
        for (int ns = 0; ns < 4; ++ns)
            acc[ns] = __builtin_amdgcn_mfma_f32_16x16x32_bf16(a_cur, b_cur[ns], acc[ns], 0, 0, 0);
        a_cur = a_nxt;
#pragma unroll
        for (int ns = 0; ns < 4; ++ns) b_cur[ns] = b_nxt[ns];
    }
#pragma unroll
    for (int ns = 0; ns < 4; ++ns)
        acc[ns] = __builtin_amdgcn_mfma_f32_16x16x32_bf16(a_cur, b_cur[ns], acc[ns], 0, 0, 0);

#pragma unroll
    for (int ns = 0; ns < 4; ++ns) {
        const int n = n0 + ns * 16 + col;
        const float bias = b2[n];
#pragma unroll
        for (int r = 0; r < 4; ++r) {
            const int m = m0 + kq * 4 + r;
            const float val = acc[ns][r] + bias;
            fz[m * DIMD + n] = val;
            if (write_zb)
                zb[m * DIMD + n] = f2bf(x[m * DIMD + n] + cnext * val);
        }
    }
}

// ---------------- K4: RK4 combine + output --------------------------------
__global__ __launch_bounds__(256) void k_out(
    const float* __restrict__ x, const float* __restrict__ fz,
    const float* __restrict__ divacc, float* __restrict__ out)
{
    const int idx = blockIdx.x * 256 + threadIdx.x;
    const int TOT = BATCH * (DIMD + 1);
    if (idx >= TOT) return;
    const int b = idx / (DIMD + 1);
    const int c = idx - b * (DIMD + 1);
    const float sixth = 1.0f / 6.0f;
    if (c < DIMD) {
        float xv = x[b * DIMD + c];
        int o = b * DIMD + c;
        float f1 = fz[o];
        float f2 = fz[BATCH * DIMD + o];
        float f3 = fz[2 * BATCH * DIMD + o];
        float f4 = fz[3 * BATCH * DIMD + o];
        out[idx] = xv;
        out[TOT + idx] = xv + (f1 + 2.0f * f2 + 2.0f * f3 + f4) * sixth;
    } else {
        float d1 = divacc[b];
        float d2 = divacc[BATCH + b];
        float d3 = divacc[2 * BATCH + b];
        float d4 = divacc[3 * BATCH + b];
        out[idx] = 0.0f;
        out[TOT + idx] = -(d1 + 2.0f * d2 + 2.0f * d3 + d4) * sixth;
    }
}

// ---------------- launch ---------------------------------------------------
extern "C" void kernel_launch(void* const* d_in, const int* in_sizes, int n_in,
                              void* d_out, int out_size, void* d_ws, size_t ws_size,
                              hipStream_t stream) {
    const float* x  = (const float*)d_in[0];
    const float* W1 = (const float*)d_in[1];
    const float* b1 = (const float*)d_in[2];
    const float* W2 = (const float*)d_in[3];
    const float* b2 = (const float*)d_in[4];
    float* out = (float*)d_out;

    char* ws = (char*)d_ws;
    short* hb    = (short*)(ws);                   // 8 MiB
    float* fz    = (float*)(ws + 8388608);         // 16 MiB
    short* zb    = (short*)(ws + 25165824);        // 2 MiB
    short* w1t   = (short*)(ws + 27262976);        // 512 KiB
    short* w2b   = (short*)(ws + 27787264);        // 512 KiB
    short* w2t   = (short*)(ws + 28311552);        // 512 KiB
    float* dv    = (float*)(ws + 28835840);        // 64 KiB
    uint64_t* ep = (uint64_t*)(ws + 28901376);     // 4*10*4096*256/8 = 5.25 MiB

    // Host-side threefry key derivation (partitionable semantics):
    //   fk_i = tf((0,42),(0,i));  k2_i = tf(fk_i,(0,1))
    Keys4 keys;
    for (uint32_t i = 0; i < 4; ++i) {
        uint32_t f0, f1, g0, g1;
        tf2x32(0u, 42u, 0u, i, f0, f1);
        tf2x32(f0, f1, 0u, 1u, g0, g1);
        keys.a[i] = g0;
        keys.b[i] = g1;
    }

    // 1851392 prep items + 10485760 stage-0 egen items = 12337152 = 48192*256
    k_prep<<<48192, 256, 0, stream>>>(x, W1, W2, w1t, w2b, w2t, zb, dv,
                                      ep, keys.a[0], keys.b[0]);

    const float tvals[4] = {0.0f, 0.5f, 0.5f, 1.0f};
    const float cnext[4] = {0.5f, 0.5f, 1.0f, 0.0f};  // Zb_{s+1} = x + cnext*fz_s
    for (int s = 0; s < 4; ++s) {
        const int last = (s == 3);
        k_pre_div<<<dim3(16, 64), 256, 0, stream>>>(
            zb, w1t, w2b, W1, b1, tvals[s], ep + (size_t)s * NEPW,
            hb, dv + (size_t)s * BATCH,
            ep + (size_t)(s + 1) * NEPW,
            last ? 0u : keys.a[s + 1], last ? 0u : keys.b[s + 1],
            last ? 0 : 1);
        k_fz2<<<256, 256, 0, stream>>>(hb, w2t, b2, x,
                                       fz + (size_t)s * BATCH * DIMD,
                                       cnext[s], (s < 3) ? 1 : 0, zb);
    }
    int tot = BATCH * (DIMD + 1);
    k_out<<<(tot + 255) / 256, 256, 0, stream>>>(x, fz, dv, out);
}